// Round 6
// baseline (640.835 us; speedup 1.0000x reference)
//
#include <hip/hip_runtime.h>
#include <hip/hip_bf16.h>
#include <stdint.h>

#define LOG2E 1.44269504088896340736f
#define LN2   0.69314718055994530942f

typedef __attribute__((ext_vector_type(8))) __bf16 bf16x8;
typedef __attribute__((ext_vector_type(4))) float  f32x4;

static constexpr int B = 128, S = 512, T = 256;
static constexpr int LDP = T + 8;   // padded LDS row (bf16 elems)

static __device__ __forceinline__ uint pack_bf16x2(float a, float b) {
    __hip_bfloat162 h = __float22bfloat162_rn(make_float2(a, b));
    union { __hip_bfloat162 h; uint u; } cv; cv.h = h;
    return cv.u;
}
static __device__ __forceinline__ float bf2f(ushort u) {
    return __uint_as_float(((uint)u) << 16);
}

// ---------------- prep: Et[j][i] = bf16( exp(trans[i][j]) ) ----------------
__global__ void prep_Et(const float* __restrict__ trans, ushort* __restrict__ Et) {
    int j = blockIdx.x;    // 256
    int i = threadIdx.x;   // 256
    float e = exp2f(trans[i * T + j] * LOG2E);
    uint u = __float_as_uint(e);
    Et[j * T + i] = (ushort)((u + 0x7FFFu + ((u >> 16) & 1u)) >> 16);  // RTNE
}

// ---------------- prep: emx = bf16( exp(em) ), elementwise over B*S*T ----------------
__global__ void prep_emx(const float* __restrict__ em, ushort* __restrict__ emx) {
    size_t i4 = ((size_t)blockIdx.x * blockDim.x + threadIdx.x) * 4;
    f32x4 e = *reinterpret_cast<const f32x4*>(&em[i4]);
    uint2 w;
    w.x = pack_bf16x2(exp2f(e[0] * LOG2E), exp2f(e[1] * LOG2E));
    w.y = pack_bf16x2(exp2f(e[2] * LOG2E), exp2f(e[3] * LOG2E));
    *reinterpret_cast<uint2*>(&emx[i4]) = w;
}

// ---------------- main scan: one WG per (scan, batch-group of 16) ----------------
// 512 thr / 8 waves, j split 8 ways (32 states per wave, 2 m-tiles) -> 2 waves
// per SIMD interleave independent per-step work (R4 showed +34%/CU from 2
// waves/SIMD; here without halving active CUs). Group-of-4 delayed renorm
// (exact power-of-2), em/mask batched per 8 steps with register ping-pong.
// Both scans instruction-identical when mask==1 -> bitwise-identical results.
template<bool PRE>
__launch_bounds__(512, 2)
__global__ void crf_scan(const float* __restrict__ em,      // [B][S][T] fp32
                         const ushort* __restrict__ emx,    // [B][S][T] bf16 exp(em) (PRE)
                         const int* __restrict__ mask,      // [B][S] int32
                         const float* __restrict__ startt,  // [T]
                         const float* __restrict__ endt,    // [T]
                         const ushort* __restrict__ Et,     // [T][T] bf16, Et[j][i]=exp(trans[i][j])
                         float* __restrict__ res)           // [2][B] log2-domain results
{
    const int tid  = threadIdx.x;
    const int w    = tid >> 6;          // wave 0..7: j-range [32w, 32w+32)
    const int lane = tid & 63;
    const int q    = lane >> 4;         // quad 0..3
    const int l    = lane & 15;         // local batch 0..15
    const int scan = blockIdx.x & 1;
    const int bg   = blockIdx.x >> 1;   // 0..7
    const int b    = bg * 16 + l;       // this lane's batch (MFMA N index)

    __shared__ __align__(16) ushort Al[2][16][LDP];   // alpha, bf16, double-buffered
    __shared__ __align__(16) float mx2[16][8];        // [batch][wave] stored-alpha max

    // ---- Et fragments (A-operand, step-invariant): 64 VGPRs/wave.
    bf16x8 Afr[2][8];
    #pragma unroll
    for (int mt = 0; mt < 2; ++mt) {
        int j = w * 32 + mt * 16 + l;
        #pragma unroll
        for (int kt = 0; kt < 8; ++kt)
            Afr[mt][kt] = *reinterpret_cast<const bf16x8*>(&Et[j * T + kt * 32 + q * 8]);
    }

    const float*  emrow = em  + (size_t)b * S * T;
    const ushort* exrow = PRE ? emx + (size_t)b * S * T : nullptr;
    const int*    mrow  = mask + (size_t)b * S;

    int ls = 0;
    int buf = 0;

    // ---- init: alpha0 = exp(start + em[:,0]), normalized once
    {
        float v0[2][4]; float mx = 0.0f;
        #pragma unroll
        for (int t = 0; t < 2; ++t) {
            int j0 = w * 32 + t * 16 + q * 4;
            f32x4 e4 = *reinterpret_cast<const f32x4*>(&emrow[j0]);
            f32x4 s4 = *reinterpret_cast<const f32x4*>(&startt[j0]);
            #pragma unroll
            for (int r = 0; r < 4; ++r) {
                v0[t][r] = exp2f((e4[r] + s4[r]) * LOG2E);
                mx = fmaxf(mx, v0[t][r]);
            }
        }
        mx = fmaxf(mx, __shfl_xor(mx, 16));
        mx = fmaxf(mx, __shfl_xor(mx, 32));
        if (q == 0) mx2[l][w] = mx;
        __syncthreads();
        f32x4 ma = *reinterpret_cast<const f32x4*>(&mx2[l][0]);
        f32x4 mb = *reinterpret_cast<const f32x4*>(&mx2[l][4]);
        float gmx = fmaxf(fmaxf(fmaxf(ma[0], ma[1]), fmaxf(ma[2], ma[3])),
                          fmaxf(fmaxf(mb[0], mb[1]), fmaxf(mb[2], mb[3])));
        int e = (int)((__float_as_uint(gmx) >> 23) & 255u) - 127;
        float sc = __uint_as_float((uint)(127 - e) << 23);   // exact 2^-e
        ls = e;
        #pragma unroll
        for (int t = 0; t < 2; ++t) {
            int j0 = w * 32 + t * 16 + q * 4;
            uint2 wd;
            wd.x = pack_bf16x2(v0[t][0] * sc, v0[t][1] * sc);
            wd.y = pack_bf16x2(v0[t][2] * sc, v0[t][3] * sc);
            *reinterpret_cast<uint2*>(&Al[0][l][j0]) = wd;
        }
        __syncthreads();
        if (q == 0) mx2[l][w] = mx * sc;   // max of stored alpha0
        __syncthreads();
    }

    // ---- batched em/mask registers, ping-pong A/B
    uint2 exA[8][2], exB[8][2]; int mkA[8], mkB[8];

    // preload group 0 (steps 1..8) into A
    #pragma unroll
    for (int u = 0; u < 8; ++u) {
        int s = 1 + u;
        #pragma unroll
        for (int t = 0; t < 2; ++t) {
            int j0 = w * 32 + t * 16 + q * 4;
            if (PRE) exA[u][t] = *reinterpret_cast<const uint2*>(&exrow[(size_t)s * T + j0]);
        }
        mkA[u] = scan ? mrow[s] : 1;
    }

    auto run_group = [&](uint2 (&exv)[8][2], int (&mks)[8],
                         uint2 (&exn)[8][2], int (&mkn)[8], int p) {
        // issue next group's loads now; they complete during step u=0
        const int base = 9 + 8 * p;
        #pragma unroll
        for (int u = 0; u < 8; ++u) {
            int su  = base + u;
            int suc = su < S ? su : S - 1;
            #pragma unroll
            for (int t = 0; t < 2; ++t) {
                int j0 = w * 32 + t * 16 + q * 4;
                if (PRE) exn[u][t] = *reinterpret_cast<const uint2*>(&exrow[(size_t)suc * T + j0]);
            }
            mkn[u] = (scan && su < S) ? mrow[su] : 1;
        }

        float pend = 1.0f, vml = 0.0f; int pk = 0;

        #pragma unroll
        for (int u = 0; u < 8; ++u) {
            const int s = 1 + 8 * p + u;
            if (s < S) {
                if ((u & 3) == 0) {   // renorm-group start: derive kappa
                    f32x4 ma = *reinterpret_cast<const f32x4*>(&mx2[l][0]);
                    f32x4 mb = *reinterpret_cast<const f32x4*>(&mx2[l][4]);
                    float gmx = fmaxf(fmaxf(fmaxf(ma[0], ma[1]), fmaxf(ma[2], ma[3])),
                                      fmaxf(fmaxf(mb[0], mb[1]), fmaxf(mb[2], mb[3])));
                    int kap = (int)((__float_as_uint(gmx) >> 23) & 255u) - 127;
                    pend = __uint_as_float((uint)(127 - kap) << 23);   // exact 2^-kap
                    pk   = kap;
                    vml  = gmx;
                }
                const int nb = buf ^ 1;

                // MFMA: P[j][b] = sum_i Et[j][i] * alpha_stored[b][i]
                f32x4 acc[2] = {f32x4{0,0,0,0}, f32x4{0,0,0,0}};
                #pragma unroll
                for (int kt = 0; kt < 8; ++kt) {
                    bf16x8 bfr = *reinterpret_cast<const bf16x8*>(&Al[buf][l][kt * 32 + q * 8]);
                    #pragma unroll
                    for (int mt = 0; mt < 2; ++mt)
                        acc[mt] = __builtin_amdgcn_mfma_f32_16x16x32_bf16(Afr[mt][kt], bfr, acc[mt], 0, 0, 0);
                }

                // epilogue: v = acc * exp(em) * pend
                const int mk = mks[u];
                float v[2][4]; float lmx = 0.0f;
                #pragma unroll
                for (int t = 0; t < 2; ++t) {
                    if (PRE) {
                        v[t][0] = acc[t][0] * bf2f((ushort)(exv[u][t].x & 0xFFFF)) * pend;
                        v[t][1] = acc[t][1] * bf2f((ushort)(exv[u][t].x >> 16))    * pend;
                        v[t][2] = acc[t][2] * bf2f((ushort)(exv[u][t].y & 0xFFFF)) * pend;
                        v[t][3] = acc[t][3] * bf2f((ushort)(exv[u][t].y >> 16))    * pend;
                    } else {
                        int j0 = w * 32 + t * 16 + q * 4;
                        f32x4 e4 = *reinterpret_cast<const f32x4*>(&emrow[(size_t)s * T + j0]);
                        #pragma unroll
                        for (int r = 0; r < 4; ++r)
                            v[t][r] = acc[t][r] * exp2f(e4[r] * LOG2E) * pend;
                    }
                    #pragma unroll
                    for (int r = 0; r < 4; ++r) lmx = fmaxf(lmx, v[t][r]);
                }

                if (mk) {
                    #pragma unroll
                    for (int t = 0; t < 2; ++t) {
                        int j0 = w * 32 + t * 16 + q * 4;
                        uint2 wd;
                        wd.x = pack_bf16x2(v[t][0], v[t][1]);
                        wd.y = pack_bf16x2(v[t][2], v[t][3]);
                        *reinterpret_cast<uint2*>(&Al[nb][l][j0]) = wd;
                    }
                } else {
                    #pragma unroll
                    for (int t = 0; t < 2; ++t) {
                        int j0 = w * 32 + t * 16 + q * 4;
                        *reinterpret_cast<uint2*>(&Al[nb][l][j0]) =
                            *reinterpret_cast<const uint2*>(&Al[buf][l][j0]);
                    }
                }
                // bookkeeping (mask-generic; uniform across the wave per l)
                ls  += mk ? pk : 0;
                vml  = mk ? lmx : vml;
                pend = mk ? 1.0f : pend;
                pk   = mk ? 0 : pk;

                const bool rn = ((u & 3) == 3) || (s == S - 1);
                if (rn) {   // publish stored-alpha max for next renorm group
                    float m2 = fmaxf(vml, __shfl_xor(vml, 16));
                    m2 = fmaxf(m2, __shfl_xor(m2, 32));
                    if (q == 0) mx2[l][w] = m2;
                }

                __syncthreads();
                buf = nb;
            }
        }
    };

    for (int pp = 0; pp < 32; ++pp) {
        run_group(exA, mkA, exB, mkB, 2 * pp);
        run_group(exB, mkB, exA, mkA, 2 * pp + 1);
    }

    // ---- final: res = ls + log2( sum_j alpha_stored[b][j] * exp(end[j]) )
    float part = 0.0f;
    #pragma unroll
    for (int kt = 0; kt < 8; ++kt) {
        int i0 = kt * 32 + q * 8;
        f32x4 ea = *reinterpret_cast<const f32x4*>(&endt[i0]);
        f32x4 eb = *reinterpret_cast<const f32x4*>(&endt[i0 + 4]);
        ushort4 a0 = *reinterpret_cast<const ushort4*>(&Al[buf][l][i0]);
        ushort4 a1 = *reinterpret_cast<const ushort4*>(&Al[buf][l][i0 + 4]);
        part += bf2f(a0.x) * exp2f(ea[0] * LOG2E);
        part += bf2f(a0.y) * exp2f(ea[1] * LOG2E);
        part += bf2f(a0.z) * exp2f(ea[2] * LOG2E);
        part += bf2f(a0.w) * exp2f(ea[3] * LOG2E);
        part += bf2f(a1.x) * exp2f(eb[0] * LOG2E);
        part += bf2f(a1.y) * exp2f(eb[1] * LOG2E);
        part += bf2f(a1.z) * exp2f(eb[2] * LOG2E);
        part += bf2f(a1.w) * exp2f(eb[3] * LOG2E);
    }
    part += __shfl_xor(part, 16);
    part += __shfl_xor(part, 32);

    if (w == 0 && q == 0)
        res[scan * B + b] = (float)ls + log2f(part);
}

// ---------------- combine: out[b] = (partition - score) * ln2 ----------------
__global__ void combine(const float* __restrict__ res, float* __restrict__ out) {
    int b = threadIdx.x;  // 128
    out[b] = (res[b] - res[B + b]) * LN2;
}

extern "C" void kernel_launch(void* const* d_in, const int* in_sizes, int n_in,
                              void* d_out, int out_size, void* d_ws, size_t ws_size,
                              hipStream_t stream) {
    (void)in_sizes; (void)n_in; (void)out_size;
    const float* em = (const float*)d_in[0];
    const int*   mk = (const int*)d_in[1];
    const float* st = (const float*)d_in[2];
    const float* en = (const float*)d_in[3];
    const float* tr = (const float*)d_in[4];

    const size_t emx_bytes = (size_t)B * S * T * sizeof(ushort);   // 32 MiB
    ushort* emx = (ushort*)d_ws;
    ushort* Et  = (ushort*)((char*)d_ws + emx_bytes);              // 128 KiB
    float*  res = (float*)((char*)d_ws + emx_bytes + (T * T * sizeof(ushort)));
    const bool pre = ws_size >= emx_bytes + T * T * sizeof(ushort) + 4096;

    if (pre) {
        prep_Et<<<T, T, 0, stream>>>(tr, Et);
        prep_emx<<<(B * S * T) / (256 * 4), 256, 0, stream>>>(em, emx);
        crf_scan<true><<<16, 512, 0, stream>>>(em, emx, mk, st, en, Et, res);
    } else {
        Et  = (ushort*)d_ws;
        res = (float*)((char*)d_ws + (T * T * sizeof(ushort)));
        prep_Et<<<T, T, 0, stream>>>(tr, Et);
        crf_scan<false><<<16, 512, 0, stream>>>(em, emx, mk, st, en, Et, res);
    }
    combine<<<1, B, 0, stream>>>(res, (float*)d_out);
}